// Round 12
// baseline (155.308 us; speedup 1.0000x reference)
//
#include <hip/hip_runtime.h>
#include <hip/hip_bf16.h>
#include <hip/hip_fp16.h>

typedef float f32x4 __attribute__((ext_vector_type(4)));
typedef float f32x16 __attribute__((ext_vector_type(16)));
typedef short s16x8 __attribute__((ext_vector_type(8)));
typedef _Float16 f16x8 __attribute__((ext_vector_type(8)));

// ---- workspace layout (bytes) ----
#define OFF_EMBT   0u         // bf16 [2][2][256][512]  (embT[b][A/B][n][e])
#define OFF_W1T    1048576u   // bf16 [600][512]        (W1T[c][e])
#define OFF_W2TSW  1662976u   // f16 swizzled [19][4][64] uint4  (32x32x16 B-frags, padded 304x128)
#define OFF_W0BF   1740800u   // bf16 [64][512]
#define OFF_HA     1806336u   // f16 FRAGMENT layout [2][4][8 it][19 ks][64 lane][8]
#define OFF_R2     3051520u   // f32 [2][256][256]
#define OFF_PNPK   3575808u   // bf16 packed pn weights
#define WS_TOTAL   3739648u

__device__ __forceinline__ int pack_bf2(float a, float b) {
  __hip_bfloat162 h = __float22bfloat162_rn(make_float2(a, b));
  int r; __builtin_memcpy(&r, &h, 4); return r;
}
__device__ __forceinline__ unsigned pack_f16_2(float a, float b) {
  __half2 h = __float22half2_rn(make_float2(a, b));
  unsigned r; __builtin_memcpy(&r, &h, 4); return r;
}
__device__ __forceinline__ unsigned short bf16u(float f) {
  __hip_bfloat16 h = __float2bfloat16(f);
  unsigned short u; __builtin_memcpy(&u, &h, 2); return u;
}
// DPP add-reduce helpers (VALU pipe, not LDS)
template<int CTRL>
__device__ __forceinline__ float dpp_add(float x) {
  int xi; __builtin_memcpy(&xi, &x, 4);
  int yi = __builtin_amdgcn_update_dpp(0, xi, CTRL, 0xf, 0xf, true);
  float y; __builtin_memcpy(&y, &yi, 4);
  return x + y;
}
__device__ __forceinline__ float swz_xor16(float x) {
  int xi; __builtin_memcpy(&xi, &x, 4);
  int yi = __builtin_amdgcn_ds_swizzle(xi, 0x401f);  // lane ^ 16
  float y; __builtin_memcpy(&y, &yi, 4);
  return y;
}

// ================= KA: pack / transpose prep =================
__global__ __launch_bounds__(256) void ka_prep(
    const float* __restrict__ act_emb, const float* __restrict__ anc_emb,
    const float* __restrict__ W1, const float* __restrict__ W2,
    const float* __restrict__ W0pn,
    const float* __restrict__ pnW1, const float* __restrict__ pnW2,
    const float* __restrict__ pnW3, const float* __restrict__ pnW4,
    char* __restrict__ ws)
{
  __hip_bfloat16* embT  = (__hip_bfloat16*)(ws + OFF_EMBT);
  __hip_bfloat16* W1T   = (__hip_bfloat16*)(ws + OFF_W1T);
  unsigned short* W2Tsw = (unsigned short*)(ws + OFF_W2TSW);
  unsigned short* W0bf  = (unsigned short*)(ws + OFF_W0BF);
  __shared__ float tile[64][65];
  int blk = blockIdx.x, t = threadIdx.x;
  if (blk < 128) {
    int b = blk >> 6, emb = (blk >> 5) & 1, ntile = (blk >> 3) & 3, etile = blk & 7;
    const float* src = emb ? anc_emb : act_emb;
    int e0 = etile * 64, n0 = ntile * 64;
    int rr = t >> 6, cc = t & 63;
    #pragma unroll
    for (int it2 = 0; it2 < 16; ++it2) {
      int e_l = rr * 16 + it2;
      tile[e_l][cc] = src[(size_t)(b * 512 + e0 + e_l) * 256 + n0 + cc];
    }
    __syncthreads();
    int n_l = t >> 2, eq = t & 3;
    unsigned int* dst = (unsigned int*)(embT + ((size_t)((b * 2 + emb) * 256 + n0 + n_l)) * 512 + e0 + eq * 16);
    #pragma unroll
    for (int kk = 0; kk < 8; ++kk)
      dst[kk] = (unsigned)pack_bf2(tile[eq * 16 + 2 * kk][n_l], tile[eq * 16 + 2 * kk + 1][n_l]);
  } else if (blk < 208) {
    int id = blk - 128;
    int half = id / 40; int rem = id % 40; int et = rem / 5; int ct = rem % 5;
    int e0 = et * 64, c0 = ct * 64;
    int rr = t >> 6, cc = t & 63;
    #pragma unroll
    for (int it2 = 0; it2 < 16; ++it2) {
      int e_l = rr * 16 + it2;
      int c = c0 + cc;
      tile[e_l][cc] = (c < 300) ? W1[(size_t)(half * 512 + e0 + e_l) * 300 + c] : 0.f;
    }
    __syncthreads();
    int c_l = t >> 2, eq = t & 3;
    if (c0 + c_l < 300) {
      unsigned int* dst = (unsigned int*)(W1T + ((size_t)(half * 300 + c0 + c_l)) * 512 + e0 + eq * 16);
      #pragma unroll
      for (int kk = 0; kk < 8; ++kk)
        dst[kk] = (unsigned)pack_bf2(tile[eq * 16 + 2 * kk][c_l], tile[eq * 16 + 2 * kk + 1][c_l]);
    }
  } else if (blk < 227) {
    int idx = (blk - 208) * 256 + t;  // [0, 4864)
    int lane = idx & 63; int ntks = idx >> 6; int nt = ntks & 3; int ks = ntks >> 2;
    int n = nt * 32 + (lane & 31);
    int kb = ks * 16 + (lane >> 5) * 8;
    unsigned int q[4];
    #pragma unroll
    for (int jj = 0; jj < 4; ++jj) {
      int k0 = kb + jj * 2, k1 = kb + jj * 2 + 1;
      float f0 = (n < 100 && k0 < 300) ? W2[(size_t)k0 * 100 + n] : 0.f;
      float f1 = (n < 100 && k1 < 300) ? W2[(size_t)k1 * 100 + n] : 0.f;
      q[jj] = pack_f16_2(f0, f1);
    }
    ((uint4*)W2Tsw)[idx] = make_uint4(q[0], q[1], q[2], q[3]);
  } else if (blk < 243) {
    int idx = (blk - 227) * 256 + t;   // [0, 4096)
    const float* s = W0pn + (size_t)idx * 8;
    ((uint4*)W0bf)[idx] = make_uint4(
        (unsigned)pack_bf2(s[0], s[1]), (unsigned)pack_bf2(s[2], s[3]),
        (unsigned)pack_bf2(s[4], s[5]), (unsigned)pack_bf2(s[6], s[7]));
  } else if (blk < 247) {
    int idx = (blk - 243) * 256 + t;  // [0,1024)
    _Float16* haf = (_Float16*)(ws + OFF_HA);
    #pragma unroll
    for (int u2 = 0; u2 < 2; ++u2) {
      int unit = idx * 2 + u2;
      int combo = unit >> 5, row = unit & 31;
      size_t off = (((size_t)combo * 19 + 18) << 9) + (1 << 8) + (row << 3) + 4;
      unsigned* p = (unsigned*)(haf + off);
      p[0] = 0u; p[1] = 0u;
    }
  } else {
    int idx = (blk - 247) * 256 + t;  // [0, 10240)
    const float* s;
    if (idx < 512)       s = pnW1 + (size_t)idx * 8;
    else if (idx < 1024) s = pnW2 + (size_t)(idx - 512) * 8;
    else if (idx < 2048) s = pnW3 + (size_t)(idx - 1024) * 8;
    else                 s = pnW4 + (size_t)(idx - 2048) * 8;
    unsigned short* pnPK = (unsigned short*)(ws + OFF_PNPK);
    ((uint4*)pnPK)[idx] = make_uint4(
        (unsigned)pack_bf2(s[0], s[1]), (unsigned)pack_bf2(s[2], s[3]),
        (unsigned)pack_bf2(s[4], s[5]), (unsigned)pack_bf2(s[6], s[7]));
  }
}

// ================= PointNet layer helper (bf16 pre-packed weights) =====
template<int K, int NT>
__device__ __forceinline__ void pn_layer(unsigned short* xb, const unsigned short* __restrict__ Wp,
                                         const float* __restrict__ bias, int wv, int l, int g)
{
  constexpr int NN = NT / 4;
  f32x4 z = {0.f, 0.f, 0.f, 0.f};
  f32x4 acc[NN];
  #pragma unroll
  for (int nn = 0; nn < NN; ++nn) acc[nn] = z;
  #pragma unroll
  for (int nn = 0; nn < NN; ++nn) {
    int o = (wv + nn * 4) * 16 + l;
    const unsigned short* wr0 = Wp + (size_t)o * K;
    #pragma unroll
    for (int ks = 0; ks < K / 32; ++ks) {
      int koff = ks * 32 + g * 8;
      s16x8 bfr = *(const s16x8*)(wr0 + koff);
      s16x8 a0 = *(const s16x8*)(xb + (size_t)l * 520 + koff);
      acc[nn] = __builtin_amdgcn_mfma_f32_16x16x32_bf16(a0, bfr, acc[nn], 0, 0, 0);
    }
  }
  __syncthreads();
  #pragma unroll
  for (int nn = 0; nn < NN; ++nn) {
    int chan = (wv + nn * 4) * 16 + l;
    float bv = bias[chan];
    #pragma unroll
    for (int r = 0; r < 4; ++r)
      xb[(size_t)(g * 4 + r) * 520 + chan] = bf16u(fmaxf(acc[nn][r] + bv, 0.f));
  }
  __syncthreads();
}

// ================= K1: PointNet (blocks 0..31) + hA GEMMs (32..351) =====
// GEMM ks-loop FULLY UNROLLED (R11 model: addressing VALU dominated; A-row
// spans 1024B so every load folds to one base + imm offset). The ok[]-select
// is dropped: garbage B columns (c in [600,608)) only reach acc columns the
// write-guard never stores; reads stay inside ws.
__global__ __launch_bounds__(256) void k1_ha(
    const __hip_bfloat16* __restrict__ embT, const __hip_bfloat16* __restrict__ W1T,
    const float* __restrict__ b1, _Float16* __restrict__ ha_f,
    const unsigned short* __restrict__ W0bf, const unsigned short* __restrict__ pnPK,
    const float* __restrict__ pnB0, const float* __restrict__ pnB1,
    const float* __restrict__ pnB2, const float* __restrict__ pnB3,
    const float* __restrict__ pnB4,
    const float* __restrict__ headW, float* __restrict__ out)
{
  __shared__ unsigned short xbuf[16 * 520];
  int blk = blockIdx.x, t = threadIdx.x;
  int wv = t >> 6, lane = t & 63, l = lane & 15, g = lane >> 4;
  if (blk >= 32) {
    int gb = blk - 32;
    int b = gb / 160; int r = gb % 160; int emb = r / 80; r %= 80;
    int mch = r / 5; int nch = r % 5;
    int m0 = mch * 16;
    const unsigned short* Ap = (const unsigned short*)embT +
        ((size_t)((b * 2 + emb) * 256 + m0 + l)) * 512 + g * 8;
    const unsigned short* Wp = (const unsigned short*)W1T;
    // per-q B row pointers (c may reach 607; reads stay in ws, cols unused)
    const unsigned short* Bq0 = Wp + (size_t)(nch * 120 + (wv * 2 + 0) * 16 + l) * 512 + g * 8;
    const unsigned short* Bq1 = Wp + (size_t)(nch * 120 + (wv * 2 + 1) * 16 + l) * 512 + g * 8;
    f32x4 z = {0.f, 0.f, 0.f, 0.f};
    f32x4 acc[2] = {z, z};
    #pragma unroll
    for (int ks = 0; ks < 16; ++ks) {
      int k0 = ks * 32;
      s16x8 af  = *(const s16x8*)(Ap + k0);
      s16x8 bf0 = *(const s16x8*)(Bq0 + k0);
      s16x8 bf1 = *(const s16x8*)(Bq1 + k0);
      acc[0] = __builtin_amdgcn_mfma_f32_16x16x32_bf16(af, bf0, acc[0], 0, 0, 0);
      acc[1] = __builtin_amdgcn_mfma_f32_16x16x32_bf16(af, bf1, acc[1], 0, 0, 0);
    }
    #pragma unroll
    for (int q = 0; q < 2; ++q) {
      int cl = (wv * 2 + q) * 16 + l;
      int c = nch * 120 + cl;
      if (cl < 120 && c < 600) {
        int half = (c >= 300) ? 1 : 0;
        int cc = c - half * 300;
        float bias = (emb == 0) ? b1[cc] : 0.f;
        int d = emb * 2 + half;
        int ksf = cc >> 4, hi2 = (cc >> 3) & 1, e = cc & 7;
        #pragma unroll
        for (int r2 = 0; r2 < 4; ++r2) {
          int i = m0 + g * 4 + r2;
          size_t off = (((((size_t)(b * 4 + d)) * 8 + (i >> 5)) * 19 + ksf) << 9)
                     + (hi2 << 8) + ((i & 31) << 3) + e;
          ha_f[off] = (_Float16)__float2half_rn(acc[q][r2] + bias);
        }
      }
    }
  } else {
    // ---- PointNet: 32 blocks, each 16 points ----
    int pn = blk;
    int b_pn = pn >> 4, n0 = (pn & 15) * 16;
    unsigned short* xb = xbuf;
    {
      const unsigned short* A0 = (const unsigned short*)embT + ((size_t)(b_pn * 2 * 256 + n0)) * 512;
      f32x4 acc0 = {0.f, 0.f, 0.f, 0.f};
      int o = wv * 16 + l;
      const unsigned short* w0r = W0bf + (size_t)o * 512;
      #pragma unroll
      for (int ks = 0; ks < 16; ++ks) {
        int koff = ks * 32 + g * 8;
        s16x8 bfr = *(const s16x8*)(w0r + koff);
        s16x8 a0 = *(const s16x8*)(A0 + (size_t)l * 512 + koff);
        acc0 = __builtin_amdgcn_mfma_f32_16x16x32_bf16(a0, bfr, acc0, 0, 0, 0);
      }
      float bv = pnB0[o];
      #pragma unroll
      for (int r2 = 0; r2 < 4; ++r2)
        xb[(size_t)(g * 4 + r2) * 520 + o] = bf16u(fmaxf(acc0[r2] + bv, 0.f));
      __syncthreads();
    }
    pn_layer<64, 4>(xb, pnPK, pnB1, wv, l, g);
    pn_layer<64, 4>(xb, pnPK + 4096, pnB2, wv, l, g);
    pn_layer<64, 8>(xb, pnPK + 8192, pnB3, wv, l, g);
    pn_layer<128, 32>(xb, pnPK + 16384, pnB4, wv, l, g);
    {
      int p_l = t >> 4, os = t & 15;
      const unsigned short* row = xb + (size_t)p_l * 520 + os * 32;
      float s = 0.f;
      #pragma unroll
      for (int c = 0; c < 32; ++c) {
        unsigned int u = ((unsigned int)row[c]) << 16;
        float xv; __builtin_memcpy(&xv, &u, 4);
        s += xv * headW[os * 32 + c];
      }
      s += __shfl_xor(s, 1); s += __shfl_xor(s, 2);
      s += __shfl_xor(s, 4); s += __shfl_xor(s, 8);
      if (os == 0) out[(size_t)(b_pn * 4 + 3) * 256 + n0 + p_l] = s;
    }
  }
}

// ================= K2: pairwise MLP tail (fully unrolled ks) ============
// R11 model: VALUBusy 3x my static count -> address arithmetic for 6
// 64-bit pointer streams inside the #pragma unroll 1 loop is the dominant
// VALU. Full unroll makes every offset a compile-time constant (compiler
// folds to imm offsets / few rebased pointers) and lets it software-
// pipeline loads itself (G7). acc 64 + hoisted loads ~24-48 + bases ~10
// ~= 140-160 regs < 168 cap at (256,3) -> no spill expected (tripwire:
// symmetric FETCH/WRITE growth).
__global__ __launch_bounds__(256, 3) void k2_main(
    const _Float16* __restrict__ haF, const unsigned short* __restrict__ W2Tsw,
    const float* __restrict__ b2g, const float* __restrict__ W3g, const float* __restrict__ b3g,
    float* __restrict__ R2)
{
  __shared__ float ex[2][2][16];  // [jl][hi][col] nt-half exchange, 256 B
  int blkp = blockIdx.x, t = threadIdx.x;
  int blk = (blkp & 7) * 256 + (blkp >> 3);  // XCD-grouping (2048 = 8*256, bijective)
  int wv = t >> 6, lane = t & 63, col = lane & 31, hi = lane >> 5;
  int jl = wv & 1, nh = wv >> 1;
  int u = blk; int b = u >> 10; u &= 1023; int it = u >> 7; int jt = u & 127;
  int i0 = it * 32;
  int j = jt * 2 + jl;
  const int4* w2g = (const int4*)W2Tsw + nh * 128 + lane;
  const _Float16* pA0 = haF + ((((size_t)(b * 4 + 0)) * 8 + it) * 19) * 512 + lane * 8;  // hAa+b1
  const _Float16* pA1 = haF + ((((size_t)(b * 4 + 1)) * 8 + it) * 19) * 512 + lane * 8;  // hAb+b1
  const _Float16* pB0 = haF + ((((size_t)(b * 4 + 3)) * 8 + (j >> 5)) * 19) * 512
                        + (hi * 32 + (j & 31)) * 8;                                      // hBb (dir0)
  const _Float16* pB1 = haF + ((((size_t)(b * 4 + 2)) * 8 + (j >> 5)) * 19) * 512
                        + (hi * 32 + (j & 31)) * 8;                                      // hBa (dir1)
  const f16x8 zf = {0, 0, 0, 0, 0, 0, 0, 0};
  f32x16 z16;
  #pragma unroll
  for (int q = 0; q < 16; ++q) z16[q] = 0.f;
  f32x16 a00 = z16, a01 = z16, a10 = z16, a11 = z16;

  #pragma unroll
  for (int ks = 0; ks < 19; ++ks) {
    int ko = ks * 512;
    f16x8 a0 = *(const f16x8*)(pA0 + ko);
    f16x8 a1 = *(const f16x8*)(pA1 + ko);
    f16x8 b0 = *(const f16x8*)(pB0 + ko);
    f16x8 b1 = *(const f16x8*)(pB1 + ko);
    const int4* wn = w2g + ks * 256;
    f16x8 w0 = *(const f16x8*)(wn);
    f16x8 w1 = *(const f16x8*)(wn + 64);
    f16x8 af0 = __builtin_elementwise_max(a0 + b0, zf);  // relu(hAa+b1 + hBb) = v1 input
    f16x8 af1 = __builtin_elementwise_max(a1 + b1, zf);  // relu(hAb+b1 + hBa) = v2 input
    a00 = __builtin_amdgcn_mfma_f32_32x32x16_f16(af0, w0, a00, 0, 0, 0);
    a10 = __builtin_amdgcn_mfma_f32_32x32x16_f16(af1, w0, a10, 0, 0, 0);
    a01 = __builtin_amdgcn_mfma_f32_32x32x16_f16(af0, w1, a01, 0, 0, 0);
    a11 = __builtin_amdgcn_mfma_f32_32x32x16_f16(af1, w1, a11, 0, 0, 0);
  }
  // ---- epilogue: dirs merged in-wave; nt-halves merged via ex[] ----
  {
    int n0 = (nh * 2) * 32 + col, n1 = n0 + 32;
    float w3v0 = (n0 < 100) ? W3g[n0] : 0.f;
    float w3v1 = (n1 < 100) ? W3g[n1] : 0.f;
    float b2v0 = (n0 < 100) ? b2g[n0] : 0.f;
    float b2v1 = (n1 < 100) ? b2g[n1] : 0.f;
    float b3 = b3g[0];
    // D layout (32x32): n = nt*32 + col, i = (r&3) + 8*(r>>2) + 4*hi
    float mine = 0.f;
    #pragma unroll
    for (int r = 0; r < 16; ++r) {
      float x = fmaxf(a00[r] + b2v0, 0.f) * w3v0 + fmaxf(a01[r] + b2v1, 0.f) * w3v1
              + fmaxf(a10[r] + b2v0, 0.f) * w3v0 + fmaxf(a11[r] + b2v1, 0.f) * w3v1;
      x = dpp_add<0xB1>(x);   // quad_perm xor1
      x = dpp_add<0x4E>(x);   // quad_perm xor2
      x = dpp_add<0x141>(x);  // row_half_mirror (8-groups)
      x = dpp_add<0x140>(x);  // row_mirror (16-groups)
      x += swz_xor16(x);
      if (col == r) mine = x;  // lane col<16 keeps reg r=col's sum
    }
    __syncthreads();
    if (nh == 1 && col < 16) ex[jl][hi][col] = mine;
    __syncthreads();
    if (nh == 0 && col < 16) {
      float tot = mine + ex[jl][hi][col];
      float S = 0.5f * tot + b3;
      float Rr = (S > 20.f) ? S : log1pf(expf(S));
      int il = (col & 3) + 8 * (col >> 2) + 4 * hi;
      R2[((size_t)(b * 256 + i0 + il)) * 256 + j] = Rr * Rr;
    }
  }
}

// ================= K3: multilateration solve =================
__device__ __forceinline__ float block_sum(float v, float* redbuf, int t) {
  #pragma unroll
  for (int m = 1; m < 64; m <<= 1) v += __shfl_xor(v, m);
  __syncthreads();
  if ((t & 63) == 0) redbuf[t >> 6] = v;
  __syncthreads();
  return redbuf[0] + redbuf[1] + redbuf[2] + redbuf[3];
}

__global__ __launch_bounds__(256) void k3_solve(
    const float* __restrict__ anc_pts, const float* __restrict__ act_pts,
    const float* __restrict__ R2, float* __restrict__ out)
{
  __shared__ float Ax[256], Ay[256], Az[256];
  __shared__ float redbuf[4];
  int blk = blockIdx.x, t = threadIdx.x;
  int b = blk >> 5, ic = blk & 31;
  int k = t;
  float px = anc_pts[(size_t)(b * 3 + 0) * 256 + k];
  float py = anc_pts[(size_t)(b * 3 + 1) * 256 + k];
  float pz = anc_pts[(size_t)(b * 3 + 2) * 256 + k];
  float qx = block_sum(px, redbuf, t) * (1.f / 256.f);
  float qy = block_sum(py, redbuf, t) * (1.f / 256.f);
  float qz = block_sum(pz, redbuf, t) * (1.f / 256.f);
  float ax = 2.f * (px - qx), ay = 2.f * (py - qy), az = 2.f * (pz - qz);
  float p2 = px * px + py * py + pz * pz;
  Ax[k] = ax; Ay[k] = ay; Az[k] = az;
  float mxx = block_sum(ax * ax, redbuf, t);
  float mxy = block_sum(ax * ay, redbuf, t);
  float mxz = block_sum(ax * az, redbuf, t);
  float myy = block_sum(ay * ay, redbuf, t);
  float myz = block_sum(ay * az, redbuf, t);
  float mzz = block_sum(az * az, redbuf, t);
  float c0x = block_sum(ax * p2, redbuf, t);
  float c0y = block_sum(ay * p2, redbuf, t);
  float c0z = block_sum(az * p2, redbuf, t);
  __syncthreads();
  float det = mxx * (myy * mzz - myz * myz) - mxy * (mxy * mzz - myz * mxz) + mxz * (mxy * myz - myy * mxz);
  float idet = 1.f / det;
  float i00 = (myy * mzz - myz * myz) * idet;
  float i01 = (mxz * myz - mxy * mzz) * idet;
  float i02 = (mxy * myz - mxz * myy) * idet;
  float i11 = (mxx * mzz - mxz * mxz) * idet;
  float i12 = (mxy * mxz - mxx * myz) * idet;
  float i22 = (mxx * myy - mxy * mxy) * idet;
  int il = t >> 5, ksq = t & 31;
  int i = ic * 8 + il;
  const float* rrow = R2 + ((size_t)(b * 256 + i)) * 256;
  float r0 = 0.f, r1 = 0.f, r2 = 0.f;
  #pragma unroll
  for (int kk = 0; kk < 2; ++kk) {
    int kb = ksq * 8 + kk * 4;
    f32x4 rv = *(const f32x4*)(rrow + kb);
    r0 += Ax[kb] * rv.x + Ax[kb + 1] * rv.y + Ax[kb + 2] * rv.z + Ax[kb + 3] * rv.w;
    r1 += Ay[kb] * rv.x + Ay[kb + 1] * rv.y + Ay[kb + 2] * rv.z + Ay[kb + 3] * rv.w;
    r2 += Az[kb] * rv.x + Az[kb + 1] * rv.y + Az[kb + 2] * rv.z + Az[kb + 3] * rv.w;
  }
  r0 += __shfl_xor(r0, 1); r0 += __shfl_xor(r0, 2); r0 += __shfl_xor(r0, 4);
  r0 += __shfl_xor(r0, 8); r0 += __shfl_xor(r0, 16);
  r1 += __shfl_xor(r1, 1); r1 += __shfl_xor(r1, 2); r1 += __shfl_xor(r1, 4);
  r1 += __shfl_xor(r1, 8); r1 += __shfl_xor(r1, 16);
  r2 += __shfl_xor(r2, 1); r2 += __shfl_xor(r2, 2); r2 += __shfl_xor(r2, 4);
  r2 += __shfl_xor(r2, 8); r2 += __shfl_xor(r2, 16);
  if (ksq == 0) {
    float hx = c0x - r0, hy = c0y - r1, hz = c0z - r2;
    float x0 = i00 * hx + i01 * hy + i02 * hz;
    float x1 = i01 * hx + i11 * hy + i12 * hz;
    float x2 = i02 * hx + i12 * hy + i22 * hz;
    out[(size_t)(b * 4 + 0) * 256 + i] = x0 - act_pts[(size_t)(b * 3 + 0) * 256 + i];
    out[(size_t)(b * 4 + 1) * 256 + i] = x1 - act_pts[(size_t)(b * 3 + 1) * 256 + i];
    out[(size_t)(b * 4 + 2) * 256 + i] = x2 - act_pts[(size_t)(b * 3 + 2) * 256 + i];
  }
}

extern "C" void kernel_launch(void* const* d_in, const int* in_sizes, int n_in,
                              void* d_out, int out_size, void* d_ws, size_t ws_size,
                              hipStream_t stream)
{
  const float* act_emb = (const float*)d_in[0];
  const float* anc_emb = (const float*)d_in[1];
  const float* act_pts = (const float*)d_in[2];
  const float* anc_pts = (const float*)d_in[3];
  const float* W1  = (const float*)d_in[4];
  const float* b1  = (const float*)d_in[5];
  const float* W2  = (const float*)d_in[6];
  const float* b2  = (const float*)d_in[7];
  const float* W3  = (const float*)d_in[8];
  const float* b3  = (const float*)d_in[9];
  const float* pnW0 = (const float*)d_in[10];
  const float* pnB0 = (const float*)d_in[11];
  const float* pnW1 = (const float*)d_in[12];
  const float* pnB1 = (const float*)d_in[13];
  const float* pnW2 = (const float*)d_in[14];
  const float* pnB2 = (const float*)d_in[15];
  const float* pnW3 = (const float*)d_in[16];
  const float* pnB3 = (const float*)d_in[17];
  const float* pnW4 = (const float*)d_in[18];
  const float* pnB4 = (const float*)d_in[19];
  const float* headW = (const float*)d_in[20];
  char* ws = (char*)d_ws;
  __hip_bfloat16* embT  = (__hip_bfloat16*)(ws + OFF_EMBT);
  __hip_bfloat16* W1T   = (__hip_bfloat16*)(ws + OFF_W1T);
  unsigned short* W2Tsw = (unsigned short*)(ws + OFF_W2TSW);
  unsigned short* W0bf  = (unsigned short*)(ws + OFF_W0BF);
  unsigned short* pnPK  = (unsigned short*)(ws + OFF_PNPK);
  _Float16* ha_f = (_Float16*)(ws + OFF_HA);
  float* R2ws  = (float*)(ws + OFF_R2);
  float* outp  = (float*)d_out;

  ka_prep<<<287, 256, 0, stream>>>(act_emb, anc_emb, W1, W2, pnW0,
                                   pnW1, pnW2, pnW3, pnW4, ws);
  k1_ha<<<352, 256, 0, stream>>>(embT, W1T, b1, ha_f, W0bf, pnPK,
                                 pnB0, pnB1, pnB2, pnB3, pnB4,
                                 headW, outp);
  k2_main<<<2048, 256, 0, stream>>>(ha_f, W2Tsw, b2, W3, b3, R2ws);
  k3_solve<<<64, 256, 0, stream>>>(anc_pts, act_pts, R2ws, outp);
}

// Round 13
// 152.835 us; speedup vs baseline: 1.0162x; 1.0162x over previous
//
#include <hip/hip_runtime.h>
#include <hip/hip_bf16.h>
#include <hip/hip_fp16.h>

typedef float f32x4 __attribute__((ext_vector_type(4)));
typedef float f32x16 __attribute__((ext_vector_type(16)));
typedef short s16x8 __attribute__((ext_vector_type(8)));
typedef _Float16 f16x8 __attribute__((ext_vector_type(8)));

// ---- workspace layout (bytes) ----
#define OFF_EMBT   0u         // bf16 [2][2][256][512]  (embT[b][A/B][n][e])
#define OFF_W1T    1048576u   // bf16 [600][512]        (W1T[c][e])
#define OFF_W2TSW  1662976u   // f16 swizzled [19][4][64] uint4  (32x32x16 B-frags, padded 304x128)
#define OFF_W0BF   1740800u   // bf16 [64][512]
#define OFF_HA     1806336u   // f16 FRAGMENT layout [2][4][8 it][19 ks][64 lane][8]
#define OFF_R2     3051520u   // f32 [2][256][256]
#define OFF_PNPK   3575808u   // bf16 packed pn weights
#define WS_TOTAL   3739648u

__device__ __forceinline__ int pack_bf2(float a, float b) {
  __hip_bfloat162 h = __float22bfloat162_rn(make_float2(a, b));
  int r; __builtin_memcpy(&r, &h, 4); return r;
}
__device__ __forceinline__ unsigned pack_f16_2(float a, float b) {
  __half2 h = __float22half2_rn(make_float2(a, b));
  unsigned r; __builtin_memcpy(&r, &h, 4); return r;
}
__device__ __forceinline__ unsigned short bf16u(float f) {
  __hip_bfloat16 h = __float2bfloat16(f);
  unsigned short u; __builtin_memcpy(&u, &h, 2); return u;
}
// DPP add-reduce helpers (VALU pipe, not LDS)
template<int CTRL>
__device__ __forceinline__ float dpp_add(float x) {
  int xi; __builtin_memcpy(&xi, &x, 4);
  int yi = __builtin_amdgcn_update_dpp(0, xi, CTRL, 0xf, 0xf, true);
  float y; __builtin_memcpy(&y, &yi, 4);
  return x + y;
}
__device__ __forceinline__ float swz_xor16(float x) {
  int xi; __builtin_memcpy(&xi, &x, 4);
  int yi = __builtin_amdgcn_ds_swizzle(xi, 0x401f);  // lane ^ 16
  float y; __builtin_memcpy(&y, &yi, 4);
  return y;
}

// ================= KA: pack / transpose prep =================
__global__ __launch_bounds__(256) void ka_prep(
    const float* __restrict__ act_emb, const float* __restrict__ anc_emb,
    const float* __restrict__ W1, const float* __restrict__ W2,
    const float* __restrict__ W0pn,
    const float* __restrict__ pnW1, const float* __restrict__ pnW2,
    const float* __restrict__ pnW3, const float* __restrict__ pnW4,
    char* __restrict__ ws)
{
  __hip_bfloat16* embT  = (__hip_bfloat16*)(ws + OFF_EMBT);
  __hip_bfloat16* W1T   = (__hip_bfloat16*)(ws + OFF_W1T);
  unsigned short* W2Tsw = (unsigned short*)(ws + OFF_W2TSW);
  unsigned short* W0bf  = (unsigned short*)(ws + OFF_W0BF);
  __shared__ float tile[64][65];
  int blk = blockIdx.x, t = threadIdx.x;
  if (blk < 128) {
    int b = blk >> 6, emb = (blk >> 5) & 1, ntile = (blk >> 3) & 3, etile = blk & 7;
    const float* src = emb ? anc_emb : act_emb;
    int e0 = etile * 64, n0 = ntile * 64;
    int rr = t >> 6, cc = t & 63;
    #pragma unroll
    for (int it2 = 0; it2 < 16; ++it2) {
      int e_l = rr * 16 + it2;
      tile[e_l][cc] = src[(size_t)(b * 512 + e0 + e_l) * 256 + n0 + cc];
    }
    __syncthreads();
    int n_l = t >> 2, eq = t & 3;
    unsigned int* dst = (unsigned int*)(embT + ((size_t)((b * 2 + emb) * 256 + n0 + n_l)) * 512 + e0 + eq * 16);
    #pragma unroll
    for (int kk = 0; kk < 8; ++kk)
      dst[kk] = (unsigned)pack_bf2(tile[eq * 16 + 2 * kk][n_l], tile[eq * 16 + 2 * kk + 1][n_l]);
  } else if (blk < 208) {
    int id = blk - 128;
    int half = id / 40; int rem = id % 40; int et = rem / 5; int ct = rem % 5;
    int e0 = et * 64, c0 = ct * 64;
    int rr = t >> 6, cc = t & 63;
    #pragma unroll
    for (int it2 = 0; it2 < 16; ++it2) {
      int e_l = rr * 16 + it2;
      int c = c0 + cc;
      tile[e_l][cc] = (c < 300) ? W1[(size_t)(half * 512 + e0 + e_l) * 300 + c] : 0.f;
    }
    __syncthreads();
    int c_l = t >> 2, eq = t & 3;
    if (c0 + c_l < 300) {
      unsigned int* dst = (unsigned int*)(W1T + ((size_t)(half * 300 + c0 + c_l)) * 512 + e0 + eq * 16);
      #pragma unroll
      for (int kk = 0; kk < 8; ++kk)
        dst[kk] = (unsigned)pack_bf2(tile[eq * 16 + 2 * kk][c_l], tile[eq * 16 + 2 * kk + 1][c_l]);
    }
  } else if (blk < 227) {
    int idx = (blk - 208) * 256 + t;  // [0, 4864)
    int lane = idx & 63; int ntks = idx >> 6; int nt = ntks & 3; int ks = ntks >> 2;
    int n = nt * 32 + (lane & 31);
    int kb = ks * 16 + (lane >> 5) * 8;
    unsigned int q[4];
    #pragma unroll
    for (int jj = 0; jj < 4; ++jj) {
      int k0 = kb + jj * 2, k1 = kb + jj * 2 + 1;
      float f0 = (n < 100 && k0 < 300) ? W2[(size_t)k0 * 100 + n] : 0.f;
      float f1 = (n < 100 && k1 < 300) ? W2[(size_t)k1 * 100 + n] : 0.f;
      q[jj] = pack_f16_2(f0, f1);
    }
    ((uint4*)W2Tsw)[idx] = make_uint4(q[0], q[1], q[2], q[3]);
  } else if (blk < 243) {
    int idx = (blk - 227) * 256 + t;   // [0, 4096)
    const float* s = W0pn + (size_t)idx * 8;
    ((uint4*)W0bf)[idx] = make_uint4(
        (unsigned)pack_bf2(s[0], s[1]), (unsigned)pack_bf2(s[2], s[3]),
        (unsigned)pack_bf2(s[4], s[5]), (unsigned)pack_bf2(s[6], s[7]));
  } else if (blk < 247) {
    int idx = (blk - 243) * 256 + t;  // [0,1024)
    _Float16* haf = (_Float16*)(ws + OFF_HA);
    #pragma unroll
    for (int u2 = 0; u2 < 2; ++u2) {
      int unit = idx * 2 + u2;
      int combo = unit >> 5, row = unit & 31;
      size_t off = (((size_t)combo * 19 + 18) << 9) + (1 << 8) + (row << 3) + 4;
      unsigned* p = (unsigned*)(haf + off);
      p[0] = 0u; p[1] = 0u;
    }
  } else {
    int idx = (blk - 247) * 256 + t;  // [0, 10240)
    const float* s;
    if (idx < 512)       s = pnW1 + (size_t)idx * 8;
    else if (idx < 1024) s = pnW2 + (size_t)(idx - 512) * 8;
    else if (idx < 2048) s = pnW3 + (size_t)(idx - 1024) * 8;
    else                 s = pnW4 + (size_t)(idx - 2048) * 8;
    unsigned short* pnPK = (unsigned short*)(ws + OFF_PNPK);
    ((uint4*)pnPK)[idx] = make_uint4(
        (unsigned)pack_bf2(s[0], s[1]), (unsigned)pack_bf2(s[2], s[3]),
        (unsigned)pack_bf2(s[4], s[5]), (unsigned)pack_bf2(s[6], s[7]));
  }
}

// ================= PointNet layer helper (bf16 pre-packed weights) =====
template<int K, int NT>
__device__ __forceinline__ void pn_layer(unsigned short* xb, const unsigned short* __restrict__ Wp,
                                         const float* __restrict__ bias, int wv, int l, int g)
{
  constexpr int NN = NT / 4;
  f32x4 z = {0.f, 0.f, 0.f, 0.f};
  f32x4 acc[NN];
  #pragma unroll
  for (int nn = 0; nn < NN; ++nn) acc[nn] = z;
  #pragma unroll
  for (int nn = 0; nn < NN; ++nn) {
    int o = (wv + nn * 4) * 16 + l;
    const unsigned short* wr0 = Wp + (size_t)o * K;
    #pragma unroll
    for (int ks = 0; ks < K / 32; ++ks) {
      int koff = ks * 32 + g * 8;
      s16x8 bfr = *(const s16x8*)(wr0 + koff);
      s16x8 a0 = *(const s16x8*)(xb + (size_t)l * 520 + koff);
      acc[nn] = __builtin_amdgcn_mfma_f32_16x16x32_bf16(a0, bfr, acc[nn], 0, 0, 0);
    }
  }
  __syncthreads();
  #pragma unroll
  for (int nn = 0; nn < NN; ++nn) {
    int chan = (wv + nn * 4) * 16 + l;
    float bv = bias[chan];
    #pragma unroll
    for (int r = 0; r < 4; ++r)
      xb[(size_t)(g * 4 + r) * 520 + chan] = bf16u(fmaxf(acc[nn][r] + bv, 0.f));
  }
  __syncthreads();
}

// ================= K1: PointNet (blocks 0..31) + hA GEMMs (32..351) =====
// R12's k1 kept: fully unrolled ks (imm-folded addressing) + ok[]-select
// dropped (garbage cols never stored; reads stay in ws).
__global__ __launch_bounds__(256) void k1_ha(
    const __hip_bfloat16* __restrict__ embT, const __hip_bfloat16* __restrict__ W1T,
    const float* __restrict__ b1, _Float16* __restrict__ ha_f,
    const unsigned short* __restrict__ W0bf, const unsigned short* __restrict__ pnPK,
    const float* __restrict__ pnB0, const float* __restrict__ pnB1,
    const float* __restrict__ pnB2, const float* __restrict__ pnB3,
    const float* __restrict__ pnB4,
    const float* __restrict__ headW, float* __restrict__ out)
{
  __shared__ unsigned short xbuf[16 * 520];
  int blk = blockIdx.x, t = threadIdx.x;
  int wv = t >> 6, lane = t & 63, l = lane & 15, g = lane >> 4;
  if (blk >= 32) {
    int gb = blk - 32;
    int b = gb / 160; int r = gb % 160; int emb = r / 80; r %= 80;
    int mch = r / 5; int nch = r % 5;
    int m0 = mch * 16;
    const unsigned short* Ap = (const unsigned short*)embT +
        ((size_t)((b * 2 + emb) * 256 + m0 + l)) * 512 + g * 8;
    const unsigned short* Wp = (const unsigned short*)W1T;
    const unsigned short* Bq0 = Wp + (size_t)(nch * 120 + (wv * 2 + 0) * 16 + l) * 512 + g * 8;
    const unsigned short* Bq1 = Wp + (size_t)(nch * 120 + (wv * 2 + 1) * 16 + l) * 512 + g * 8;
    f32x4 z = {0.f, 0.f, 0.f, 0.f};
    f32x4 acc[2] = {z, z};
    #pragma unroll
    for (int ks = 0; ks < 16; ++ks) {
      int k0 = ks * 32;
      s16x8 af  = *(const s16x8*)(Ap + k0);
      s16x8 bf0 = *(const s16x8*)(Bq0 + k0);
      s16x8 bf1 = *(const s16x8*)(Bq1 + k0);
      acc[0] = __builtin_amdgcn_mfma_f32_16x16x32_bf16(af, bf0, acc[0], 0, 0, 0);
      acc[1] = __builtin_amdgcn_mfma_f32_16x16x32_bf16(af, bf1, acc[1], 0, 0, 0);
    }
    #pragma unroll
    for (int q = 0; q < 2; ++q) {
      int cl = (wv * 2 + q) * 16 + l;
      int c = nch * 120 + cl;
      if (cl < 120 && c < 600) {
        int half = (c >= 300) ? 1 : 0;
        int cc = c - half * 300;
        float bias = (emb == 0) ? b1[cc] : 0.f;
        int d = emb * 2 + half;
        int ksf = cc >> 4, hi2 = (cc >> 3) & 1, e = cc & 7;
        #pragma unroll
        for (int r2 = 0; r2 < 4; ++r2) {
          int i = m0 + g * 4 + r2;
          size_t off = (((((size_t)(b * 4 + d)) * 8 + (i >> 5)) * 19 + ksf) << 9)
                     + (hi2 << 8) + ((i & 31) << 3) + e;
          ha_f[off] = (_Float16)__float2half_rn(acc[q][r2] + bias);
        }
      }
    }
  } else {
    // ---- PointNet: 32 blocks, each 16 points ----
    int pn = blk;
    int b_pn = pn >> 4, n0 = (pn & 15) * 16;
    unsigned short* xb = xbuf;
    {
      const unsigned short* A0 = (const unsigned short*)embT + ((size_t)(b_pn * 2 * 256 + n0)) * 512;
      f32x4 acc0 = {0.f, 0.f, 0.f, 0.f};
      int o = wv * 16 + l;
      const unsigned short* w0r = W0bf + (size_t)o * 512;
      #pragma unroll
      for (int ks = 0; ks < 16; ++ks) {
        int koff = ks * 32 + g * 8;
        s16x8 bfr = *(const s16x8*)(w0r + koff);
        s16x8 a0 = *(const s16x8*)(A0 + (size_t)l * 512 + koff);
        acc0 = __builtin_amdgcn_mfma_f32_16x16x32_bf16(a0, bfr, acc0, 0, 0, 0);
      }
      float bv = pnB0[o];
      #pragma unroll
      for (int r2 = 0; r2 < 4; ++r2)
        xb[(size_t)(g * 4 + r2) * 520 + o] = bf16u(fmaxf(acc0[r2] + bv, 0.f));
      __syncthreads();
    }
    pn_layer<64, 4>(xb, pnPK, pnB1, wv, l, g);
    pn_layer<64, 4>(xb, pnPK + 4096, pnB2, wv, l, g);
    pn_layer<64, 8>(xb, pnPK + 8192, pnB3, wv, l, g);
    pn_layer<128, 32>(xb, pnPK + 16384, pnB4, wv, l, g);
    {
      int p_l = t >> 4, os = t & 15;
      const unsigned short* row = xb + (size_t)p_l * 520 + os * 32;
      float s = 0.f;
      #pragma unroll
      for (int c = 0; c < 32; ++c) {
        unsigned int u = ((unsigned int)row[c]) << 16;
        float xv; __builtin_memcpy(&xv, &u, 4);
        s += xv * headW[os * 32 + c];
      }
      s += __shfl_xor(s, 1); s += __shfl_xor(s, 2);
      s += __shfl_xor(s, 4); s += __shfl_xor(s, 8);
      if (os == 0) out[(size_t)(b_pn * 4 + 3) * 256 + n0 + p_l] = s;
    }
  }
}

// ================= K2: pairwise MLP tail (two-bank ping-pong, R11) ======
// BEST MEASURED VARIANT (152.9us total). R12's full unroll regressed
// (+2.4us): aggressive load hoisting raised live VGPRs and cut resident
// waves. Ping-pong keeps 1-iter prefetch distance with ZERO rotation movs
// and a bounded live set (12 f16x8 = 48 + acc 64 + addr ~25 ~= 140).
__global__ __launch_bounds__(256, 3) void k2_main(
    const _Float16* __restrict__ haF, const unsigned short* __restrict__ W2Tsw,
    const float* __restrict__ b2g, const float* __restrict__ W3g, const float* __restrict__ b3g,
    float* __restrict__ R2)
{
  __shared__ float ex[2][2][16];  // [jl][hi][col] nt-half exchange, 256 B
  int blkp = blockIdx.x, t = threadIdx.x;
  int blk = (blkp & 7) * 256 + (blkp >> 3);  // XCD-grouping (2048 = 8*256, bijective)
  int wv = t >> 6, lane = t & 63, col = lane & 31, hi = lane >> 5;
  int jl = wv & 1, nh = wv >> 1;
  int u = blk; int b = u >> 10; u &= 1023; int it = u >> 7; int jt = u & 127;
  int i0 = it * 32;
  int j = jt * 2 + jl;
  const int4* w2g = (const int4*)W2Tsw + nh * 128 + lane;
  const _Float16* pA0 = haF + ((((size_t)(b * 4 + 0)) * 8 + it) * 19) * 512 + lane * 8;  // hAa+b1
  const _Float16* pA1 = haF + ((((size_t)(b * 4 + 1)) * 8 + it) * 19) * 512 + lane * 8;  // hAb+b1
  const _Float16* pB0 = haF + ((((size_t)(b * 4 + 3)) * 8 + (j >> 5)) * 19) * 512
                        + (hi * 32 + (j & 31)) * 8;                                      // hBb (dir0)
  const _Float16* pB1 = haF + ((((size_t)(b * 4 + 2)) * 8 + (j >> 5)) * 19) * 512
                        + (hi * 32 + (j & 31)) * 8;                                      // hBa (dir1)
  const f16x8 zf = {0, 0, 0, 0, 0, 0, 0, 0};
  f32x16 z16;
  #pragma unroll
  for (int q = 0; q < 16; ++q) z16[q] = 0.f;
  f32x16 a00 = z16, a01 = z16, a10 = z16, a11 = z16;

  // bank X = even ks, bank Y = odd ks
  f16x8 a0x = *(const f16x8*)(pA0);
  f16x8 a1x = *(const f16x8*)(pA1);
  f16x8 b0x = *(const f16x8*)(pB0);
  f16x8 b1x = *(const f16x8*)(pB1);
  f16x8 w0x = *(const f16x8*)(w2g);
  f16x8 w1x = *(const f16x8*)(w2g + 64);
  f16x8 a0y, a1y, b0y, b1y, w0y, w1y;

  #pragma unroll 1
  for (int kb = 0; kb < 9; ++kb) {
    // load Y (ks = 2kb+1)
    {
      int ko = kb * 1024 + 512;
      a0y = *(const f16x8*)(pA0 + ko);
      a1y = *(const f16x8*)(pA1 + ko);
      b0y = *(const f16x8*)(pB0 + ko);
      b1y = *(const f16x8*)(pB1 + ko);
      const int4* wn = w2g + (kb * 512 + 256);
      w0y = *(const f16x8*)(wn);
      w1y = *(const f16x8*)(wn + 64);
    }
    // compute X (ks = 2kb)
    {
      f16x8 af0 = __builtin_elementwise_max(a0x + b0x, zf);
      f16x8 af1 = __builtin_elementwise_max(a1x + b1x, zf);
      a00 = __builtin_amdgcn_mfma_f32_32x32x16_f16(af0, w0x, a00, 0, 0, 0);
      a10 = __builtin_amdgcn_mfma_f32_32x32x16_f16(af1, w0x, a10, 0, 0, 0);
      a01 = __builtin_amdgcn_mfma_f32_32x32x16_f16(af0, w1x, a01, 0, 0, 0);
      a11 = __builtin_amdgcn_mfma_f32_32x32x16_f16(af1, w1x, a11, 0, 0, 0);
    }
    // load X (ks = 2kb+2) — max 18, always valid
    {
      int ko = kb * 1024 + 1024;
      a0x = *(const f16x8*)(pA0 + ko);
      a1x = *(const f16x8*)(pA1 + ko);
      b0x = *(const f16x8*)(pB0 + ko);
      b1x = *(const f16x8*)(pB1 + ko);
      const int4* wn = w2g + (kb * 512 + 512);
      w0x = *(const f16x8*)(wn);
      w1x = *(const f16x8*)(wn + 64);
    }
    // compute Y (ks = 2kb+1)
    {
      f16x8 af0 = __builtin_elementwise_max(a0y + b0y, zf);
      f16x8 af1 = __builtin_elementwise_max(a1y + b1y, zf);
      a00 = __builtin_amdgcn_mfma_f32_32x32x16_f16(af0, w0y, a00, 0, 0, 0);
      a10 = __builtin_amdgcn_mfma_f32_32x32x16_f16(af1, w0y, a10, 0, 0, 0);
      a01 = __builtin_amdgcn_mfma_f32_32x32x16_f16(af0, w1y, a01, 0, 0, 0);
      a11 = __builtin_amdgcn_mfma_f32_32x32x16_f16(af1, w1y, a11, 0, 0, 0);
    }
  }
  // tail: compute X (ks = 18)
  {
    f16x8 af0 = __builtin_elementwise_max(a0x + b0x, zf);
    f16x8 af1 = __builtin_elementwise_max(a1x + b1x, zf);
    a00 = __builtin_amdgcn_mfma_f32_32x32x16_f16(af0, w0x, a00, 0, 0, 0);
    a10 = __builtin_amdgcn_mfma_f32_32x32x16_f16(af1, w0x, a10, 0, 0, 0);
    a01 = __builtin_amdgcn_mfma_f32_32x32x16_f16(af0, w1x, a01, 0, 0, 0);
    a11 = __builtin_amdgcn_mfma_f32_32x32x16_f16(af1, w1x, a11, 0, 0, 0);
  }
  // ---- epilogue: dirs merged in-wave; nt-halves merged via ex[] ----
  {
    int n0 = (nh * 2) * 32 + col, n1 = n0 + 32;
    float w3v0 = (n0 < 100) ? W3g[n0] : 0.f;
    float w3v1 = (n1 < 100) ? W3g[n1] : 0.f;
    float b2v0 = (n0 < 100) ? b2g[n0] : 0.f;
    float b2v1 = (n1 < 100) ? b2g[n1] : 0.f;
    float b3 = b3g[0];
    // D layout (32x32): n = nt*32 + col, i = (r&3) + 8*(r>>2) + 4*hi
    float mine = 0.f;
    #pragma unroll
    for (int r = 0; r < 16; ++r) {
      float x = fmaxf(a00[r] + b2v0, 0.f) * w3v0 + fmaxf(a01[r] + b2v1, 0.f) * w3v1
              + fmaxf(a10[r] + b2v0, 0.f) * w3v0 + fmaxf(a11[r] + b2v1, 0.f) * w3v1;
      x = dpp_add<0xB1>(x);   // quad_perm xor1
      x = dpp_add<0x4E>(x);   // quad_perm xor2
      x = dpp_add<0x141>(x);  // row_half_mirror (8-groups)
      x = dpp_add<0x140>(x);  // row_mirror (16-groups)
      x += swz_xor16(x);
      if (col == r) mine = x;  // lane col<16 keeps reg r=col's sum
    }
    __syncthreads();
    if (nh == 1 && col < 16) ex[jl][hi][col] = mine;
    __syncthreads();
    if (nh == 0 && col < 16) {
      float tot = mine + ex[jl][hi][col];
      float S = 0.5f * tot + b3;
      float Rr = (S > 20.f) ? S : log1pf(expf(S));
      int il = (col & 3) + 8 * (col >> 2) + 4 * hi;
      R2[((size_t)(b * 256 + i0 + il)) * 256 + j] = Rr * Rr;
    }
  }
}

// ================= K3: multilateration solve =================
__device__ __forceinline__ float block_sum(float v, float* redbuf, int t) {
  #pragma unroll
  for (int m = 1; m < 64; m <<= 1) v += __shfl_xor(v, m);
  __syncthreads();
  if ((t & 63) == 0) redbuf[t >> 6] = v;
  __syncthreads();
  return redbuf[0] + redbuf[1] + redbuf[2] + redbuf[3];
}

__global__ __launch_bounds__(256) void k3_solve(
    const float* __restrict__ anc_pts, const float* __restrict__ act_pts,
    const float* __restrict__ R2, float* __restrict__ out)
{
  __shared__ float Ax[256], Ay[256], Az[256];
  __shared__ float redbuf[4];
  int blk = blockIdx.x, t = threadIdx.x;
  int b = blk >> 5, ic = blk & 31;
  int k = t;
  float px = anc_pts[(size_t)(b * 3 + 0) * 256 + k];
  float py = anc_pts[(size_t)(b * 3 + 1) * 256 + k];
  float pz = anc_pts[(size_t)(b * 3 + 2) * 256 + k];
  float qx = block_sum(px, redbuf, t) * (1.f / 256.f);
  float qy = block_sum(py, redbuf, t) * (1.f / 256.f);
  float qz = block_sum(pz, redbuf, t) * (1.f / 256.f);
  float ax = 2.f * (px - qx), ay = 2.f * (py - qy), az = 2.f * (pz - qz);
  float p2 = px * px + py * py + pz * pz;
  Ax[k] = ax; Ay[k] = ay; Az[k] = az;
  float mxx = block_sum(ax * ax, redbuf, t);
  float mxy = block_sum(ax * ay, redbuf, t);
  float mxz = block_sum(ax * az, redbuf, t);
  float myy = block_sum(ay * ay, redbuf, t);
  float myz = block_sum(ay * az, redbuf, t);
  float mzz = block_sum(az * az, redbuf, t);
  float c0x = block_sum(ax * p2, redbuf, t);
  float c0y = block_sum(ay * p2, redbuf, t);
  float c0z = block_sum(az * p2, redbuf, t);
  __syncthreads();
  float det = mxx * (myy * mzz - myz * myz) - mxy * (mxy * mzz - myz * mxz) + mxz * (mxy * myz - myy * mxz);
  float idet = 1.f / det;
  float i00 = (myy * mzz - myz * myz) * idet;
  float i01 = (mxz * myz - mxy * mzz) * idet;
  float i02 = (mxy * myz - mxz * myy) * idet;
  float i11 = (mxx * mzz - mxz * mxz) * idet;
  float i12 = (mxy * mxz - mxx * myz) * idet;
  float i22 = (mxx * myy - mxy * mxy) * idet;
  int il = t >> 5, ksq = t & 31;
  int i = ic * 8 + il;
  const float* rrow = R2 + ((size_t)(b * 256 + i)) * 256;
  float r0 = 0.f, r1 = 0.f, r2 = 0.f;
  #pragma unroll
  for (int kk = 0; kk < 2; ++kk) {
    int kb = ksq * 8 + kk * 4;
    f32x4 rv = *(const f32x4*)(rrow + kb);
    r0 += Ax[kb] * rv.x + Ax[kb + 1] * rv.y + Ax[kb + 2] * rv.z + Ax[kb + 3] * rv.w;
    r1 += Ay[kb] * rv.x + Ay[kb + 1] * rv.y + Ay[kb + 2] * rv.z + Ay[kb + 3] * rv.w;
    r2 += Az[kb] * rv.x + Az[kb + 1] * rv.y + Az[kb + 2] * rv.z + Az[kb + 3] * rv.w;
  }
  r0 += __shfl_xor(r0, 1); r0 += __shfl_xor(r0, 2); r0 += __shfl_xor(r0, 4);
  r0 += __shfl_xor(r0, 8); r0 += __shfl_xor(r0, 16);
  r1 += __shfl_xor(r1, 1); r1 += __shfl_xor(r1, 2); r1 += __shfl_xor(r1, 4);
  r1 += __shfl_xor(r1, 8); r1 += __shfl_xor(r1, 16);
  r2 += __shfl_xor(r2, 1); r2 += __shfl_xor(r2, 2); r2 += __shfl_xor(r2, 4);
  r2 += __shfl_xor(r2, 8); r2 += __shfl_xor(r2, 16);
  if (ksq == 0) {
    float hx = c0x - r0, hy = c0y - r1, hz = c0z - r2;
    float x0 = i00 * hx + i01 * hy + i02 * hz;
    float x1 = i01 * hx + i11 * hy + i12 * hz;
    float x2 = i02 * hx + i12 * hy + i22 * hz;
    out[(size_t)(b * 4 + 0) * 256 + i] = x0 - act_pts[(size_t)(b * 3 + 0) * 256 + i];
    out[(size_t)(b * 4 + 1) * 256 + i] = x1 - act_pts[(size_t)(b * 3 + 1) * 256 + i];
    out[(size_t)(b * 4 + 2) * 256 + i] = x2 - act_pts[(size_t)(b * 3 + 2) * 256 + i];
  }
}

extern "C" void kernel_launch(void* const* d_in, const int* in_sizes, int n_in,
                              void* d_out, int out_size, void* d_ws, size_t ws_size,
                              hipStream_t stream)
{
  const float* act_emb = (const float*)d_in[0];
  const float* anc_emb = (const float*)d_in[1];
  const float* act_pts = (const float*)d_in[2];
  const float* anc_pts = (const float*)d_in[3];
  const float* W1  = (const float*)d_in[4];
  const float* b1  = (const float*)d_in[5];
  const float* W2  = (const float*)d_in[6];
  const float* b2  = (const float*)d_in[7];
  const float* W3  = (const float*)d_in[8];
  const float* b3  = (const float*)d_in[9];
  const float* pnW0 = (const float*)d_in[10];
  const float* pnB0 = (const float*)d_in[11];
  const float* pnW1 = (const float*)d_in[12];
  const float* pnB1 = (const float*)d_in[13];
  const float* pnW2 = (const float*)d_in[14];
  const float* pnB2 = (const float*)d_in[15];
  const float* pnW3 = (const float*)d_in[16];
  const float* pnB3 = (const float*)d_in[17];
  const float* pnW4 = (const float*)d_in[18];
  const float* pnB4 = (const float*)d_in[19];
  const float* headW = (const float*)d_in[20];
  char* ws = (char*)d_ws;
  __hip_bfloat16* embT  = (__hip_bfloat16*)(ws + OFF_EMBT);
  __hip_bfloat16* W1T   = (__hip_bfloat16*)(ws + OFF_W1T);
  unsigned short* W2Tsw = (unsigned short*)(ws + OFF_W2TSW);
  unsigned short* W0bf  = (unsigned short*)(ws + OFF_W0BF);
  unsigned short* pnPK  = (unsigned short*)(ws + OFF_PNPK);
  _Float16* ha_f = (_Float16*)(ws + OFF_HA);
  float* R2ws  = (float*)(ws + OFF_R2);
  float* outp  = (float*)d_out;

  ka_prep<<<287, 256, 0, stream>>>(act_emb, anc_emb, W1, W2, pnW0,
                                   pnW1, pnW2, pnW3, pnW4, ws);
  k1_ha<<<352, 256, 0, stream>>>(embT, W1T, b1, ha_f, W0bf, pnPK,
                                 pnB0, pnB1, pnB2, pnB3, pnB4,
                                 headW, outp);
  k2_main<<<2048, 256, 0, stream>>>(ha_f, W2Tsw, b2, W3, b3, R2ws);
  k3_solve<<<64, 256, 0, stream>>>(anc_pts, act_pts, R2ws, outp);
}